// Round 6
// baseline (32423.544 us; speedup 1.0000x reference)
//
#include <hip/hip_runtime.h>
#include <cstdint>

#define HID 200
#define HALF 100
#define N_EDUS 32768
#define N_STEPS (2*N_EDUS - 1)   // 65535
#define KMAX 32766               // chain computes M_1..M_32766 (M_0 = enc[0])
#define PSTRIDE 500

typedef __fp16 h2v __attribute__((ext_vector_type(2)));   // matches cvt_pkrtz / fdot2 builtin type

// ---------------- generic tiled GEMM: C[m][n] = bias[n] + sum_k A[m][k]*B[n][k] ----------------
__global__ __launch_bounds__(256) void gemm_bt(const float* __restrict__ A, int lda,
    const float* __restrict__ B, int ldb, const float* __restrict__ bias,
    float* __restrict__ C, int ldc, int M, int N, int K)
{
    __shared__ float As[32][68];
    __shared__ float Bs[32][68];
    const int tid = threadIdx.x;
    const int tx = tid & 15, ty = tid >> 4;
    const int m0 = blockIdx.x * 64, n0 = blockIdx.y * 64;
    float acc[4][4] = {};
    for (int kc = 0; kc < K; kc += 32) {
        const int kk = tid & 31, r0 = tid >> 5;
        #pragma unroll
        for (int p = 0; p < 8; ++p) {
            const int mm = r0 + p * 8;
            const int m = m0 + mm, n = n0 + mm, kg = kc + kk;
            As[kk][mm] = (m < M && kg < K) ? A[(size_t)m * lda + kg] : 0.f;
            Bs[kk][mm] = (n < N && kg < K) ? B[(size_t)n * ldb + kg] : 0.f;
        }
        __syncthreads();
        #pragma unroll
        for (int kk2 = 0; kk2 < 32; ++kk2) {
            const float4 a = *(const float4*)&As[kk2][tx * 4];
            const float4 b = *(const float4*)&Bs[kk2][ty * 4];
            const float av[4] = {a.x, a.y, a.z, a.w};
            const float bv[4] = {b.x, b.y, b.z, b.w};
            #pragma unroll
            for (int r = 0; r < 4; ++r)
                #pragma unroll
                for (int c = 0; c < 4; ++c)
                    acc[r][c] += av[r] * bv[c];
        }
        __syncthreads();
    }
    #pragma unroll
    for (int r = 0; r < 4; ++r) {
        const int m = m0 + tx * 4 + r;
        if (m >= M) continue;
        #pragma unroll
        for (int c = 0; c < 4; ++c) {
            const int n = n0 + ty * 4 + c;
            if (n < N) C[(size_t)m * ldc + n] = acc[r][c] + (bias ? bias[n] : 0.f);
        }
    }
}

// ---------------- prep (loss weight stacking + missing projections) ----------------
__global__ void prep_kernel(const float* __restrict__ W_act, const float* __restrict__ W_lab,
    const float* __restrict__ W_dir, const float* __restrict__ miss,
    float* __restrict__ WAB, float* __restrict__ WBC,
    float* __restrict__ msAB, float* __restrict__ msBC, float* __restrict__ out)
{
    const int tid = threadIdx.x;
    if (tid == 0) out[0] = 0.f;
    for (int i = tid; i < 48 * 200; i += 256) {
        const int r = i / 200, c = i % 200;
        const int rr = r % 24;
        const float* src = (rr < 2) ? (W_act + rr * 600)
                         : (rr < 21) ? (W_lab + (rr - 2) * 600)
                                     : (W_dir + (rr - 21) * 600);
        WAB[i] = src[c + (r < 24 ? 0 : 200)];
        WBC[i] = src[c + (r < 24 ? 200 : 400)];
    }
    __syncthreads();
    if (tid < 48) {
        float sA = 0.f, sB = 0.f;
        for (int c = 0; c < 200; ++c) {
            sA += WAB[tid * 200 + c] * miss[c];
            sB += WBC[tid * 200 + c] * miss[c];
        }
        msAB[tid] = sA;
        msBC[tid] = sB;
    }
}

// ---------------- pack W_tree[:,0:100] into per-(d,q) f16-pair layout ----------------
// W16[((g*4+q)*13+t)*128 + d] = half2(W[g*100+d][2p], W[g*100+d][2p+1]), p = pst[q]+t
// zero for t >= pcnt[q] or d >= 100 (uniform 13-deep dot in chain, no divergence)
__global__ __launch_bounds__(256) void pack_w16(const float* __restrict__ W_tree,
                                                unsigned int* __restrict__ W16)
{
    const int i = blockIdx.x * 256 + threadIdx.x;   // 5*4*13*128 = 33280
    if (i >= 5 * 4 * 13 * 128) return;
    const int d = i & 127, r = i >> 7;
    const int t = r % 13, gq = r / 13, q = gq & 3, g = gq >> 2;
    const int pst[4] = {0, 13, 26, 38}, pct[4] = {13, 13, 12, 12};
    unsigned int val = 0;
    if (t < pct[q] && d < 100) {
        const int p = pst[q] + t;
        const float w0 = W_tree[(size_t)(g * 100 + d) * 200 + 2 * p];
        const float w1 = W_tree[(size_t)(g * 100 + d) * 200 + 2 * p + 1];
        h2v h = __builtin_amdgcn_cvt_pkrtz(w0, w1);
        __builtin_memcpy(&val, &h, 4);
    }
    W16[i] = val;
}

// ---------------- sequential treelstm chain ----------------
__device__ __forceinline__ float sigf(float x) {
    return __builtin_amdgcn_rcpf(1.f + __expf(-x));
}
__device__ __forceinline__ float tanhf_(float x) {
    return 1.f - 2.f * __builtin_amdgcn_rcpf(1.f + __expf(2.f * x));
}
__device__ __forceinline__ h2v u2h(unsigned int u) { h2v h; __builtin_memcpy(&h, &u, 4); return h; }

// raw barrier: drain LDS only, leave global prefetch loads (vmcnt) in flight
#define BAR() asm volatile("s_waitcnt lgkmcnt(0)\n\ts_barrier" ::: "memory")
#define KEEP(x) asm volatile("" : "+v"(x))
// quad_perm butterfly add via DPP (xor1 = 0xB1, xor2 = 0x4E) — ~4 cyc vs ~60 for ds_permute
#define DPPADD(x, c) ((x) + __int_as_float(__builtin_amdgcn_update_dpp(0, __float_as_int(x), (c), 0xF, 0xF, true)))

// 512 threads: T -> (d = T>>2 in [0,128), q = T&3). Active d<100.
// lane (d,q): 5 gate rows x 13 f16-pairs of W (65 dwords, KEEP-pinned).
// gate epilogue distributed over quad: q0=sig(i)*tanh(u), q1=sig(f1)*c1, q2=sig(f2)*c2, q3=sig(o).
__attribute__((amdgpu_waves_per_eu(2, 2)))
__global__ __launch_bounds__(512) void chain_kernel(const float* __restrict__ enc,
    const unsigned int* __restrict__ W16, const float* __restrict__ P, float* __restrict__ M)
{
    const int T = threadIdx.x;
    const int d = T >> 2, q = T & 3;
    const bool act = (d < 100);
    __shared__ float hbuf[2][128];

    if (T < 200) M[T] = enc[T];   // M_0 = enc[0]

    unsigned int W[5][13];
    #pragma unroll
    for (int g = 0; g < 5; ++g)
        #pragma unroll
        for (int t = 0; t < 13; ++t)
            W[g][t] = W16[(size_t)(((g * 4 + q) * 13 + t) * 128) + d];
    #pragma unroll
    for (int g = 0; g < 5; ++g)
        #pragma unroll
        for (int t = 0; t < 13; ++t)
            KEEP(W[g][t]);

    const int pstA[4] = {0, 13, 26, 38};
    const int hbase = 2 * pstA[q];    // float offset of this lane's h chunk
    const int goA = q * 100 + d;      // this lane's primary gate slot in a P row
    const int goB = 400 + d;          // u-gate slot (q0 only)

    float c_reg = 0.f;                                // cell state, lives at q1
    float pa_c = 0, pb_c = 0, c2_c = 0;               // step k
    float pa_1 = 0, pb_1 = 0, c2_1 = 0;               // step k+1
    if (act) {
        if (q == 1) c_reg = enc[100 + d];
        if (q == 0) hbuf[0][d] = enc[d];
        pa_c = P[(size_t)1 * PSTRIDE + goA];
        if (q == 0) pb_c = P[(size_t)1 * PSTRIDE + goB];
        if (q == 2) c2_c = enc[(size_t)1 * 200 + 100 + d];
        pa_1 = P[(size_t)2 * PSTRIDE + goA];
        if (q == 0) pb_1 = P[(size_t)2 * PSTRIDE + goB];
        if (q == 2) c2_1 = enc[(size_t)2 * 200 + 100 + d];
    }
    BAR();

    int cur = 0;
    for (int k = 1; k <= KMAX; ++k) {
        // prefetch step k+2 (2-step distance covers latency across raw barriers)
        float pa_2 = 0.f, pb_2 = 0.f, c2_2 = 0.f;
        if (act && k + 2 <= KMAX) {
            pa_2 = P[(size_t)(k + 2) * PSTRIDE + goA];
            if (q == 0) pb_2 = P[(size_t)(k + 2) * PSTRIDE + goB];
            if (q == 2) c2_2 = enc[(size_t)(k + 2) * 200 + 100 + d];
        }
        // read this lane's h chunk (f32) and pack to f16 pairs
        h2v hp[13];
        {
            const float* hb = &hbuf[cur][hbase];
            #pragma unroll
            for (int t = 0; t < 13; ++t) {
                const float2 hj = *(const float2*)(hb + 2 * t);
                hp[t] = __builtin_amdgcn_cvt_pkrtz(hj.x, hj.y);
            }
        }
        float s[5];
        #pragma unroll
        for (int g = 0; g < 5; ++g) {   // dual accumulators break the dependence chain
            float a0 = 0.f, a1 = 0.f;
            #pragma unroll
            for (int t = 0; t < 13; ++t) {
                if (t & 1) a1 = __builtin_amdgcn_fdot2(u2h(W[g][t]), hp[t], a1, false);
                else       a0 = __builtin_amdgcn_fdot2(u2h(W[g][t]), hp[t], a0, false);
            }
            s[g] = a0 + a1;
        }
        #pragma unroll
        for (int g = 0; g < 5; ++g) {   // quad butterfly via DPP
            s[g] = DPPADD(s[g], 0xB1);
            s[g] = DPPADD(s[g], 0x4E);
        }
        if (act) {
            const float prim = (q == 0) ? s[0] : (q == 1) ? s[1] : (q == 2) ? s[2] : s[3];
            const float sg = sigf(prim + pa_c);            // at q3 this is sig(o)
            const float mult = (q == 0) ? tanhf_(s[4] + pb_c)
                             : (q == 1) ? c_reg
                             : (q == 2) ? c2_c : 0.f;
            float a = sg * mult;
            a = DPPADD(a, 0xB1);
            a = DPPADD(a, 0x4E);                           // a == new cell c, all quad lanes
            if (q == 3) {
                const float h = sg * tanhf_(a);
                hbuf[cur ^ 1][d] = h;
                M[(size_t)k * 200 + d] = h;
            } else if (q == 1) {
                c_reg = a;
                M[(size_t)k * 200 + 100 + d] = a;
            }
            pa_c = pa_1; pb_c = pb_1; c2_c = c2_1;
            pa_1 = pa_2; pb_1 = pb_2; c2_1 = c2_2;
        }
        cur ^= 1;
        BAR();
    }
}

// ---------------- per-step CE losses + reduction ----------------
__global__ __launch_bounds__(256) void loss_kernel(const float* __restrict__ TM,
    const float* __restrict__ TE, const float* __restrict__ msAB, const float* __restrict__ msBC,
    const float* __restrict__ b_act, const float* __restrict__ b_lab, const float* __restrict__ b_dir,
    const int* __restrict__ ga, const int* __restrict__ gl, const int* __restrict__ gd,
    float* __restrict__ out)
{
    const int t = blockIdx.x * 256 + threadIdx.x;
    float loss = 0.f;
    if (t < N_STEPS) {
        const float *v1, *v0, *vb;
        if (t == 0)      { v1 = msAB; v0 = msAB + 24; vb = TE + 24; }
        else if (t == 1) { v1 = msAB; v0 = TE;        vb = TE + 48 + 24; }
        else if ((t & 1) == 0) {
            const int k = t >> 1;
            v1 = TM + (size_t)(k - 1) * 48;
            v0 = TE + (size_t)k * 48;
            vb = (k < N_EDUS - 1) ? (TE + (size_t)(k + 1) * 48 + 24) : (msBC + 24);
        } else {
            const int k = t >> 1;
            v1 = msAB;
            v0 = TM + (size_t)k * 48 + 24;
            vb = TE + (size_t)(k + 1) * 48 + 24;
        }
        float l[24];
        #pragma unroll
        for (int j = 0; j < 24; ++j) l[j] = v1[j] + v0[j] + vb[j];
        l[0] += b_act[0]; l[1] += b_act[1];
        #pragma unroll
        for (int j = 0; j < 19; ++j) l[2 + j] += b_lab[j];
        #pragma unroll
        for (int j = 0; j < 3; ++j) l[21 + j] += b_dir[j];
        const int ya = ga[t], yl = gl[t], yd = gd[t];
        {
            const float m = fmaxf(l[0], l[1]);
            const float sum = __expf(l[0] - m) + __expf(l[1] - m);
            loss += m + __logf(sum) - (ya == 0 ? l[0] : l[1]);
        }
        {
            float m = l[2];
            #pragma unroll
            for (int j = 1; j < 19; ++j) m = fmaxf(m, l[2 + j]);
            float sum = 0.f, ly = 0.f;
            #pragma unroll
            for (int j = 0; j < 19; ++j) {
                sum += __expf(l[2 + j] - m);
                if (j == yl) ly = l[2 + j];
            }
            loss += m + __logf(sum) - ly;
        }
        {
            const float m = fmaxf(fmaxf(l[21], l[22]), l[23]);
            const float sum = __expf(l[21] - m) + __expf(l[22] - m) + __expf(l[23] - m);
            const float ly = (yd == 0) ? l[21] : (yd == 1 ? l[22] : l[23]);
            loss += m + __logf(sum) - ly;
        }
    }
    #pragma unroll
    for (int off = 32; off > 0; off >>= 1) loss += __shfl_down(loss, off, 64);
    __shared__ float wsum[4];
    const int lane = threadIdx.x & 63, wv = threadIdx.x >> 6;
    if (lane == 0) wsum[wv] = loss;
    __syncthreads();
    if (threadIdx.x == 0) atomicAdd(out, wsum[0] + wsum[1] + wsum[2] + wsum[3]);
}

// ---------------- launch ----------------
extern "C" void kernel_launch(void* const* d_in, const int* in_sizes, int n_in,
                              void* d_out, int out_size, void* d_ws, size_t ws_size,
                              hipStream_t stream) {
    const float* enc_cls = (const float*)d_in[0];
    const float* W_proj  = (const float*)d_in[1];
    const float* b_proj  = (const float*)d_in[2];
    const float* miss    = (const float*)d_in[3];
    const float* W_act   = (const float*)d_in[4];
    const float* b_act   = (const float*)d_in[5];
    const float* W_lab   = (const float*)d_in[6];
    const float* b_lab   = (const float*)d_in[7];
    const float* W_dir   = (const float*)d_in[8];
    const float* b_dir   = (const float*)d_in[9];
    const float* W_tree  = (const float*)d_in[10];
    const float* b_tree  = (const float*)d_in[11];
    const int*   ga      = (const int*)d_in[12];
    const int*   gl      = (const int*)d_in[13];
    const int*   gd      = (const int*)d_in[14];
    float* out = (float*)d_out;

    float* ws   = (float*)d_ws;
    float* enc  = ws;                         // 32768*200            = 6,553,600
    float* Mar  = ws + 6553600;               // 32767*200            = 6,553,400
    float* P    = ws + 13107000;              // 32767*500 (row 0 unused)
    float* WAB  = ws + 29490500;              // 48*200
    float* WBC  = WAB + 9600;                 // 48*200
    float* msAB = WBC + 9600;                 // 48
    float* msBC = msAB + 48;                  // 48
    unsigned int* W16 = (unsigned int*)(msBC + 48);   // 33,280 dwords (within old high-water mark)
    float* TM = P;                            // 32767*48 (overlays dead P)
    float* TE = P + 1572816;                  // 32768*48

    gemm_bt<<<dim3(512, 4, 1), 256, 0, stream>>>(enc_cls, 768, W_proj, 768, b_proj,
                                                 enc, 200, N_EDUS, 200, 768);
    gemm_bt<<<dim3(512, 8, 1), 256, 0, stream>>>(enc + 200, 200, W_tree + 100, 200, b_tree,
                                                 P + PSTRIDE, PSTRIDE, KMAX, 500, 100);
    prep_kernel<<<1, 256, 0, stream>>>(W_act, W_lab, W_dir, miss, WAB, WBC, msAB, msBC, out);
    pack_w16<<<130, 256, 0, stream>>>(W_tree, W16);
    chain_kernel<<<1, 512, 0, stream>>>(enc, W16, P, Mar);
    gemm_bt<<<dim3(512, 1, 1), 256, 0, stream>>>(Mar, 200, WAB, 200, nullptr,
                                                 TM, 48, KMAX + 1, 48, 200);
    gemm_bt<<<dim3(512, 1, 1), 256, 0, stream>>>(enc, 200, WBC, 200, nullptr,
                                                 TE, 48, N_EDUS, 48, 200);
    loss_kernel<<<dim3(256, 1, 1), 256, 0, stream>>>(TM, TE, msAB, msBC,
                                                     b_act, b_lab, b_dir, ga, gl, gd, out);
}

// Round 7
// 25593.477 us; speedup vs baseline: 1.2669x; 1.2669x over previous
//
#include <hip/hip_runtime.h>
#include <cstdint>

#define HID 200
#define HALF 100
#define N_EDUS 32768
#define N_STEPS (2*N_EDUS - 1)   // 65535
#define KMAX 32766               // chain computes M_1..M_32766 (M_0 = enc[0])
#define PSTRIDE 500

typedef __fp16 h2v __attribute__((ext_vector_type(2)));

// ---------------- generic tiled GEMM: C[m][n] = bias[n] + sum_k A[m][k]*B[n][k] ----------------
__global__ __launch_bounds__(256) void gemm_bt(const float* __restrict__ A, int lda,
    const float* __restrict__ B, int ldb, const float* __restrict__ bias,
    float* __restrict__ C, int ldc, int M, int N, int K)
{
    __shared__ float As[32][68];
    __shared__ float Bs[32][68];
    const int tid = threadIdx.x;
    const int tx = tid & 15, ty = tid >> 4;
    const int m0 = blockIdx.x * 64, n0 = blockIdx.y * 64;
    float acc[4][4] = {};
    for (int kc = 0; kc < K; kc += 32) {
        const int kk = tid & 31, r0 = tid >> 5;
        #pragma unroll
        for (int p = 0; p < 8; ++p) {
            const int mm = r0 + p * 8;
            const int m = m0 + mm, n = n0 + mm, kg = kc + kk;
            As[kk][mm] = (m < M && kg < K) ? A[(size_t)m * lda + kg] : 0.f;
            Bs[kk][mm] = (n < N && kg < K) ? B[(size_t)n * ldb + kg] : 0.f;
        }
        __syncthreads();
        #pragma unroll
        for (int kk2 = 0; kk2 < 32; ++kk2) {
            const float4 a = *(const float4*)&As[kk2][tx * 4];
            const float4 b = *(const float4*)&Bs[kk2][ty * 4];
            const float av[4] = {a.x, a.y, a.z, a.w};
            const float bv[4] = {b.x, b.y, b.z, b.w};
            #pragma unroll
            for (int r = 0; r < 4; ++r)
                #pragma unroll
                for (int c = 0; c < 4; ++c)
                    acc[r][c] += av[r] * bv[c];
        }
        __syncthreads();
    }
    #pragma unroll
    for (int r = 0; r < 4; ++r) {
        const int m = m0 + tx * 4 + r;
        if (m >= M) continue;
        #pragma unroll
        for (int c = 0; c < 4; ++c) {
            const int n = n0 + ty * 4 + c;
            if (n < N) C[(size_t)m * ldc + n] = acc[r][c] + (bias ? bias[n] : 0.f);
        }
    }
}

// ---------------- prep (loss weight stacking + missing projections) ----------------
__global__ void prep_kernel(const float* __restrict__ W_act, const float* __restrict__ W_lab,
    const float* __restrict__ W_dir, const float* __restrict__ miss,
    float* __restrict__ WAB, float* __restrict__ WBC,
    float* __restrict__ msAB, float* __restrict__ msBC, float* __restrict__ out)
{
    const int tid = threadIdx.x;
    if (tid == 0) out[0] = 0.f;
    for (int i = tid; i < 48 * 200; i += 256) {
        const int r = i / 200, c = i % 200;
        const int rr = r % 24;
        const float* src = (rr < 2) ? (W_act + rr * 600)
                         : (rr < 21) ? (W_lab + (rr - 2) * 600)
                                     : (W_dir + (rr - 21) * 600);
        WAB[i] = src[c + (r < 24 ? 0 : 200)];
        WBC[i] = src[c + (r < 24 ? 200 : 400)];
    }
    __syncthreads();
    if (tid < 48) {
        float sA = 0.f, sB = 0.f;
        for (int c = 0; c < 200; ++c) {
            sA += WAB[tid * 200 + c] * miss[c];
            sB += WBC[tid * 200 + c] * miss[c];
        }
        msAB[tid] = sA;
        msBC[tid] = sB;
    }
}

// ---------------- pack W_tree[:,0:100] into per-(d,q) f16-pair layout ----------------
__global__ __launch_bounds__(256) void pack_w16(const float* __restrict__ W_tree,
                                                unsigned int* __restrict__ W16)
{
    const int i = blockIdx.x * 256 + threadIdx.x;   // 5*4*13*128 = 33280
    if (i >= 5 * 4 * 13 * 128) return;
    const int d = i & 127, r = i >> 7;
    const int t = r % 13, gq = r / 13, q = gq & 3, g = gq >> 2;
    const int pst[4] = {0, 13, 26, 38}, pct[4] = {13, 13, 12, 12};
    unsigned int val = 0;
    if (t < pct[q] && d < 100) {
        const int p = pst[q] + t;
        const float w0 = W_tree[(size_t)(g * 100 + d) * 200 + 2 * p];
        const float w1 = W_tree[(size_t)(g * 100 + d) * 200 + 2 * p + 1];
        h2v h = __builtin_amdgcn_cvt_pkrtz(w0, w1);
        __builtin_memcpy(&val, &h, 4);
    }
    W16[i] = val;
}

// ---------------- sequential treelstm chain ----------------
__device__ __forceinline__ float sigf(float x) {
    return __builtin_amdgcn_rcpf(1.f + __expf(-x));
}
__device__ __forceinline__ float tanhf_(float x) {
    return 1.f - 2.f * __builtin_amdgcn_rcpf(1.f + __expf(2.f * x));
}
__device__ __forceinline__ h2v u2h(unsigned int u) { h2v h; __builtin_memcpy(&h, &u, 4); return h; }

// raw barrier: drain LDS only, leave global prefetch loads (vmcnt) in flight
#define BAR() asm volatile("s_waitcnt lgkmcnt(0)\n\ts_barrier" ::: "memory")
#define KEEP(x) asm volatile("" : "+v"(x))
// quad_perm butterfly add via DPP (xor1 = 0xB1, xor2 = 0x4E)
#define DPPADD(x, c) ((x) + __int_as_float(__builtin_amdgcn_update_dpp(0, __float_as_int(x), (c), 0xF, 0xF, true)))

// One chain step. U = ring slot & buffer parity (compile-time), KK = step index.
// Consumes pa[U]/px[U] (loaded 8 steps earlier), then reissues slot U for step KK+8.
// No register rotation => compiler's s_waitcnt before consume targets 8-step-old
// loads (vmcnt stays ~16, never drains) — removes the ~900cyc/step HBM stall.
#define BODY(U, KK, DOLOAD) \
{ \
    h2v hp[13]; \
    { \
        const float* hb = &hbuf[(U) & 1][hbase]; \
        _Pragma("unroll") \
        for (int t = 0; t < 13; ++t) { \
            const float2 hj = *(const float2*)(hb + 2 * t); \
            hp[t] = __builtin_amdgcn_cvt_pkrtz(hj.x, hj.y); \
        } \
    } \
    float s[5]; \
    _Pragma("unroll") \
    for (int g = 0; g < 5; ++g) { \
        float a0 = 0.f, a1 = 0.f; \
        _Pragma("unroll") \
        for (int t = 0; t < 13; ++t) { \
            if (t & 1) a1 = __builtin_amdgcn_fdot2(u2h(W[g][t]), hp[t], a1, false); \
            else       a0 = __builtin_amdgcn_fdot2(u2h(W[g][t]), hp[t], a0, false); \
        } \
        s[g] = a0 + a1; \
    } \
    _Pragma("unroll") \
    for (int g = 0; g < 5; ++g) { s[g] = DPPADD(s[g], 0xB1); s[g] = DPPADD(s[g], 0x4E); } \
    const float prim = (q == 0) ? s[0] : (q == 1) ? s[1] : (q == 2) ? s[2] : s[3]; \
    const float sg = sigf(prim + pa[U]); \
    const float mult = (q == 0) ? tanhf_(s[4] + px[U]) \
                     : (q == 1) ? c_reg \
                     : (q == 2) ? px[U] : 0.f; \
    float a = sg * mult; \
    a = DPPADD(a, 0xB1); \
    a = DPPADD(a, 0x4E); \
    if (DOLOAD) { \
        pa[U] = pPA[(size_t)((KK) + 8) * PSTRIDE]; \
        px[U] = pPX[(size_t)((KK) + 8) * strX]; \
    } \
    if (act) { \
        if (q == 3) { \
            const float h = sg * tanhf_(a); \
            hbuf[((U) & 1) ^ 1][d] = h; \
            M[(size_t)(KK) * 200 + d] = h; \
        } else if (q == 1) { \
            c_reg = a; \
            M[(size_t)(KK) * 200 + 100 + d] = a; \
        } \
    } \
    BAR(); \
}

__attribute__((amdgpu_waves_per_eu(2, 2)))
__global__ __launch_bounds__(512) void chain_kernel(const float* __restrict__ enc,
    const unsigned int* __restrict__ W16, const float* __restrict__ P, float* __restrict__ M)
{
    const int T = threadIdx.x;
    const int d = T >> 2, q = T & 3;
    const bool act = (d < 100);
    __shared__ float hbuf[2][128];

    if (T < 200) M[T] = enc[T];   // M_0 = enc[0]

    unsigned int W[5][13];
    #pragma unroll
    for (int g = 0; g < 5; ++g)
        #pragma unroll
        for (int t = 0; t < 13; ++t)
            W[g][t] = W16[(size_t)(((g * 4 + t * 0 + q) * 13 + t) * 128) + d];
    #pragma unroll
    for (int g = 0; g < 5; ++g)
        #pragma unroll
        for (int t = 0; t < 13; ++t)
            KEEP(W[g][t]);

    const int pstA[4] = {0, 13, 26, 38};
    const int hbase = 2 * pstA[q];    // float offset of this lane's h chunk
    const int goA = q * 100 + d;      // this lane's primary gate slot in a P row

    // merged secondary stream: q0 -> P u-gate (stride 500), q2 -> enc c2 (stride 200),
    // q1/q3 -> P[0] (stride 0, dead value, keeps loads uniform & unconditional)
    const float* pPA = P + goA;
    const float* pPX = (q == 0) ? (P + 400 + d)
                     : (q == 2) ? (enc + 100 + d) : P;
    const int strX   = (q == 0) ? PSTRIDE : (q == 2) ? 200 : 0;

    float c_reg = 0.f;                 // cell state, lives at q1
    if (act) {
        if (q == 1) c_reg = enc[100 + d];
        if (q == 0) hbuf[0][d] = enc[d];
    }

    // fill the 8-deep ring: steps 1..8 -> slots 0..7
    float pa[8], px[8];
    #pragma unroll
    for (int kk = 1; kk <= 8; ++kk) {
        pa[kk - 1] = pPA[(size_t)kk * PSTRIDE];
        px[kk - 1] = pPX[(size_t)kk * strX];
    }
    BAR();

    // main loop: 4095 iterations x 8 steps = 1..32760
    for (int base = 1; base <= KMAX - 13; base += 8) {
        BODY(0, base + 0, (base + 8  <= KMAX));
        BODY(1, base + 1, (base + 9  <= KMAX));
        BODY(2, base + 2, (base + 10 <= KMAX));
        BODY(3, base + 3, (base + 11 <= KMAX));
        BODY(4, base + 4, (base + 12 <= KMAX));
        BODY(5, base + 5, (base + 13 <= KMAX));
        BODY(6, base + 6, (base + 14 <= KMAX));
        BODY(7, base + 7, (base + 15 <= KMAX));
    }
    // tail: steps 32761..32766 (slots 0..5, prefetched by the last full iteration)
    BODY(0, 32761, false);
    BODY(1, 32762, false);
    BODY(2, 32763, false);
    BODY(3, 32764, false);
    BODY(4, 32765, false);
    BODY(5, 32766, false);
}

// ---------------- per-step CE losses + reduction ----------------
__global__ __launch_bounds__(256) void loss_kernel(const float* __restrict__ TM,
    const float* __restrict__ TE, const float* __restrict__ msAB, const float* __restrict__ msBC,
    const float* __restrict__ b_act, const float* __restrict__ b_lab, const float* __restrict__ b_dir,
    const int* __restrict__ ga, const int* __restrict__ gl, const int* __restrict__ gd,
    float* __restrict__ out)
{
    const int t = blockIdx.x * 256 + threadIdx.x;
    float loss = 0.f;
    if (t < N_STEPS) {
        const float *v1, *v0, *vb;
        if (t == 0)      { v1 = msAB; v0 = msAB + 24; vb = TE + 24; }
        else if (t == 1) { v1 = msAB; v0 = TE;        vb = TE + 48 + 24; }
        else if ((t & 1) == 0) {
            const int k = t >> 1;
            v1 = TM + (size_t)(k - 1) * 48;
            v0 = TE + (size_t)k * 48;
            vb = (k < N_EDUS - 1) ? (TE + (size_t)(k + 1) * 48 + 24) : (msBC + 24);
        } else {
            const int k = t >> 1;
            v1 = msAB;
            v0 = TM + (size_t)k * 48 + 24;
            vb = TE + (size_t)(k + 1) * 48 + 24;
        }
        float l[24];
        #pragma unroll
        for (int j = 0; j < 24; ++j) l[j] = v1[j] + v0[j] + vb[j];
        l[0] += b_act[0]; l[1] += b_act[1];
        #pragma unroll
        for (int j = 0; j < 19; ++j) l[2 + j] += b_lab[j];
        #pragma unroll
        for (int j = 0; j < 3; ++j) l[21 + j] += b_dir[j];
        const int ya = ga[t], yl = gl[t], yd = gd[t];
        {
            const float m = fmaxf(l[0], l[1]);
            const float sum = __expf(l[0] - m) + __expf(l[1] - m);
            loss += m + __logf(sum) - (ya == 0 ? l[0] : l[1]);
        }
        {
            float m = l[2];
            #pragma unroll
            for (int j = 1; j < 19; ++j) m = fmaxf(m, l[2 + j]);
            float sum = 0.f, ly = 0.f;
            #pragma unroll
            for (int j = 0; j < 19; ++j) {
                sum += __expf(l[2 + j] - m);
                if (j == yl) ly = l[2 + j];
            }
            loss += m + __logf(sum) - ly;
        }
        {
            const float m = fmaxf(fmaxf(l[21], l[22]), l[23]);
            const float sum = __expf(l[21] - m) + __expf(l[22] - m) + __expf(l[23] - m);
            const float ly = (yd == 0) ? l[21] : (yd == 1 ? l[22] : l[23]);
            loss += m + __logf(sum) - ly;
        }
    }
    #pragma unroll
    for (int off = 32; off > 0; off >>= 1) loss += __shfl_down(loss, off, 64);
    __shared__ float wsum[4];
    const int lane = threadIdx.x & 63, wv = threadIdx.x >> 6;
    if (lane == 0) wsum[wv] = loss;
    __syncthreads();
    if (threadIdx.x == 0) atomicAdd(out, wsum[0] + wsum[1] + wsum[2] + wsum[3]);
}

// ---------------- launch ----------------
extern "C" void kernel_launch(void* const* d_in, const int* in_sizes, int n_in,
                              void* d_out, int out_size, void* d_ws, size_t ws_size,
                              hipStream_t stream) {
    const float* enc_cls = (const float*)d_in[0];
    const float* W_proj  = (const float*)d_in[1];
    const float* b_proj  = (const float*)d_in[2];
    const float* miss    = (const float*)d_in[3];
    const float* W_act   = (const float*)d_in[4];
    const float* b_act   = (const float*)d_in[5];
    const float* W_lab   = (const float*)d_in[6];
    const float* b_lab   = (const float*)d_in[7];
    const float* W_dir   = (const float*)d_in[8];
    const float* b_dir   = (const float*)d_in[9];
    const float* W_tree  = (const float*)d_in[10];
    const float* b_tree  = (const float*)d_in[11];
    const int*   ga      = (const int*)d_in[12];
    const int*   gl      = (const int*)d_in[13];
    const int*   gd      = (const int*)d_in[14];
    float* out = (float*)d_out;

    float* ws   = (float*)d_ws;
    float* enc  = ws;                         // 32768*200
    float* Mar  = ws + 6553600;               // 32767*200
    float* P    = ws + 13107000;              // 32767*500 (row 0 unused)
    float* WAB  = ws + 29490500;              // 48*200
    float* WBC  = WAB + 9600;                 // 48*200
    float* msAB = WBC + 9600;                 // 48
    float* msBC = msAB + 48;                  // 48
    unsigned int* W16 = (unsigned int*)(msBC + 48);   // 33,280 dwords
    float* TM = P;                            // 32767*48 (overlays dead P)
    float* TE = P + 1572816;                  // 32768*48

    gemm_bt<<<dim3(512, 4, 1), 256, 0, stream>>>(enc_cls, 768, W_proj, 768, b_proj,
                                                 enc, 200, N_EDUS, 200, 768);
    gemm_bt<<<dim3(512, 8, 1), 256, 0, stream>>>(enc + 200, 200, W_tree + 100, 200, b_tree,
                                                 P + PSTRIDE, PSTRIDE, KMAX, 500, 100);
    prep_kernel<<<1, 256, 0, stream>>>(W_act, W_lab, W_dir, miss, WAB, WBC, msAB, msBC, out);
    pack_w16<<<130, 256, 0, stream>>>(W_tree, W16);
    chain_kernel<<<1, 512, 0, stream>>>(enc, W16, P, Mar);
    gemm_bt<<<dim3(512, 1, 1), 256, 0, stream>>>(Mar, 200, WAB, 200, nullptr,
                                                 TM, 48, KMAX + 1, 48, 200);
    gemm_bt<<<dim3(512, 1, 1), 256, 0, stream>>>(enc, 200, WBC, 200, nullptr,
                                                 TE, 48, N_EDUS, 48, 200);
    loss_kernel<<<dim3(256, 1, 1), 256, 0, stream>>>(TM, TE, msAB, msBC,
                                                     b_act, b_lab, b_dir, ga, gl, gd, out);
}

// Round 8
// 20875.629 us; speedup vs baseline: 1.5532x; 1.2260x over previous
//
#include <hip/hip_runtime.h>
#include <cstdint>

#define HID 200
#define HALF 100
#define N_EDUS 32768
#define N_STEPS (2*N_EDUS - 1)   // 65535
#define KMAX 32766               // chain computes M_1..M_32766 (M_0 = enc[0])
#define PSTRIDE 500

typedef __fp16 h2v __attribute__((ext_vector_type(2)));

// ---------------- generic tiled GEMM: C[m][n] = bias[n] + sum_k A[m][k]*B[n][k] ----------------
__global__ __launch_bounds__(256) void gemm_bt(const float* __restrict__ A, int lda,
    const float* __restrict__ B, int ldb, const float* __restrict__ bias,
    float* __restrict__ C, int ldc, int M, int N, int K)
{
    __shared__ float As[32][68];
    __shared__ float Bs[32][68];
    const int tid = threadIdx.x;
    const int tx = tid & 15, ty = tid >> 4;
    const int m0 = blockIdx.x * 64, n0 = blockIdx.y * 64;
    float acc[4][4] = {};
    for (int kc = 0; kc < K; kc += 32) {
        const int kk = tid & 31, r0 = tid >> 5;
        #pragma unroll
        for (int p = 0; p < 8; ++p) {
            const int mm = r0 + p * 8;
            const int m = m0 + mm, n = n0 + mm, kg = kc + kk;
            As[kk][mm] = (m < M && kg < K) ? A[(size_t)m * lda + kg] : 0.f;
            Bs[kk][mm] = (n < N && kg < K) ? B[(size_t)n * ldb + kg] : 0.f;
        }
        __syncthreads();
        #pragma unroll
        for (int kk2 = 0; kk2 < 32; ++kk2) {
            const float4 a = *(const float4*)&As[kk2][tx * 4];
            const float4 b = *(const float4*)&Bs[kk2][ty * 4];
            const float av[4] = {a.x, a.y, a.z, a.w};
            const float bv[4] = {b.x, b.y, b.z, b.w};
            #pragma unroll
            for (int r = 0; r < 4; ++r)
                #pragma unroll
                for (int c = 0; c < 4; ++c)
                    acc[r][c] += av[r] * bv[c];
        }
        __syncthreads();
    }
    #pragma unroll
    for (int r = 0; r < 4; ++r) {
        const int m = m0 + tx * 4 + r;
        if (m >= M) continue;
        #pragma unroll
        for (int c = 0; c < 4; ++c) {
            const int n = n0 + ty * 4 + c;
            if (n < N) C[(size_t)m * ldc + n] = acc[r][c] + (bias ? bias[n] : 0.f);
        }
    }
}

// ---------------- prep (loss weight stacking + missing projections) ----------------
__global__ void prep_kernel(const float* __restrict__ W_act, const float* __restrict__ W_lab,
    const float* __restrict__ W_dir, const float* __restrict__ miss,
    float* __restrict__ WAB, float* __restrict__ WBC,
    float* __restrict__ msAB, float* __restrict__ msBC, float* __restrict__ out)
{
    const int tid = threadIdx.x;
    if (tid == 0) out[0] = 0.f;
    for (int i = tid; i < 48 * 200; i += 256) {
        const int r = i / 200, c = i % 200;
        const int rr = r % 24;
        const float* src = (rr < 2) ? (W_act + rr * 600)
                         : (rr < 21) ? (W_lab + (rr - 2) * 600)
                                     : (W_dir + (rr - 21) * 600);
        WAB[i] = src[c + (r < 24 ? 0 : 200)];
        WBC[i] = src[c + (r < 24 ? 200 : 400)];
    }
    __syncthreads();
    if (tid < 48) {
        float sA = 0.f, sB = 0.f;
        for (int c = 0; c < 200; ++c) {
            sA += WAB[tid * 200 + c] * miss[c];
            sB += WBC[tid * 200 + c] * miss[c];
        }
        msAB[tid] = sA;
        msBC[tid] = sB;
    }
}

// ---------------- pack W_tree[:,0:100] into per-(d,q) f16-pair layout ----------------
__global__ __launch_bounds__(256) void pack_w16(const float* __restrict__ W_tree,
                                                unsigned int* __restrict__ W16)
{
    const int i = blockIdx.x * 256 + threadIdx.x;   // 5*4*13*128 = 33280
    if (i >= 5 * 4 * 13 * 128) return;
    const int d = i & 127, r = i >> 7;
    const int t = r % 13, gq = r / 13, q = gq & 3, g = gq >> 2;
    const int pst[4] = {0, 13, 26, 38}, pct[4] = {13, 13, 12, 12};
    unsigned int val = 0;
    if (t < pct[q] && d < 100) {
        const int p = pst[q] + t;
        const float w0 = W_tree[(size_t)(g * 100 + d) * 200 + 2 * p];
        const float w1 = W_tree[(size_t)(g * 100 + d) * 200 + 2 * p + 1];
        h2v h = __builtin_amdgcn_cvt_pkrtz(w0, w1);
        __builtin_memcpy(&val, &h, 4);
    }
    W16[i] = val;
}

// ---------------- sequential treelstm chain ----------------
__device__ __forceinline__ float sigf(float x) {
    return __builtin_amdgcn_rcpf(1.f + __expf(-x));
}
__device__ __forceinline__ float tanhf_(float x) {
    return 1.f - 2.f * __builtin_amdgcn_rcpf(1.f + __expf(2.f * x));
}
__device__ __forceinline__ h2v u2h(unsigned int u) { h2v h; __builtin_memcpy(&h, &u, 4); return h; }

// raw barrier: drain LDS only, leave global prefetch loads (vmcnt) in flight
#define BAR() asm volatile("s_waitcnt lgkmcnt(0)\n\ts_barrier" ::: "memory")
#define KEEP(x) asm volatile("" : "+v"(x))
// quad_perm butterfly add via DPP (xor1 = 0xB1, xor2 = 0x4E)
#define DPPADD(x, c) ((x) + __int_as_float(__builtin_amdgcn_update_dpp(0, __float_as_int(x), (c), 0xF, 0xF, true)))

// One chain step. U = ring slot (0..3) & LDS parity (U&1), compile-time.
// Consumes pa[U]/px[U] (loaded 4 steps earlier), reissues slot U for step+4.
// h lives in LDS as f16 (writer-converted) -> readers get packed pairs directly.
#define BODY(U, DOLOAD) \
{ \
    const unsigned int* hb = (const unsigned int*)(&hbufh[(U) & 1][0]) + pstq; \
    unsigned int hw[13]; \
    _Pragma("unroll") \
    for (int t = 0; t < 13; ++t) hw[t] = hb[t]; \
    float ac[5] = {0.f, 0.f, 0.f, 0.f, 0.f}; \
    _Pragma("unroll") \
    for (int g = 0; g < 5; ++g) { \
        _Pragma("unroll") \
        for (int t = 0; t < 13; ++t) \
            ac[g] = __builtin_amdgcn_fdot2(u2h(W[g][t]), u2h(hw[t]), ac[g], false); \
    } \
    _Pragma("unroll") \
    for (int g = 0; g < 5; ++g) { ac[g] = DPPADD(ac[g], 0xB1); ac[g] = DPPADD(ac[g], 0x4E); } \
    const float prim = (q == 0) ? ac[0] : (q == 1) ? ac[1] : (q == 2) ? ac[2] : ac[3]; \
    const float sg = sigf(prim + pa[U]); \
    const float mult = (q == 0) ? tanhf_(ac[4] + px[U]) \
                     : (q == 1) ? c_reg \
                     : (q == 2) ? px[U] : 0.f; \
    float a = sg * mult; \
    a = DPPADD(a, 0xB1); \
    a = DPPADD(a, 0x4E); \
    if (DOLOAD) { pa[U] = *pPA; pPA += PSTRIDE; px[U] = *pPX; pPX += strX; } \
    if (q == 3) { \
        const float h = sg * tanhf_(a); \
        hbufh[((U) & 1) ^ 1][d] = (_Float16)h; \
        if (act) *pMst = h; \
    } else if (q == 1) { \
        c_reg = a; \
        if (act) *pMst = a; \
    } \
    pMst += 200; \
    BAR(); \
}

__attribute__((amdgpu_flat_work_group_size(512, 512), amdgpu_waves_per_eu(2, 2)))
__global__ void chain_kernel(const float* __restrict__ enc,
    const unsigned int* __restrict__ W16, const float* __restrict__ P, float* __restrict__ M)
{
    const int T = threadIdx.x;
    const int d = T >> 2, q = T & 3;
    const bool act = (d < 100);
    __shared__ _Float16 hbufh[2][128];

    if (T < 200) M[T] = enc[T];   // M_0 = enc[0]

    unsigned int W[5][13];
    #pragma unroll
    for (int g = 0; g < 5; ++g)
        #pragma unroll
        for (int t = 0; t < 13; ++t)
            W[g][t] = W16[(size_t)(((g * 4 + q) * 13 + t) * 128) + d];
    #pragma unroll
    for (int g = 0; g < 5; ++g)
        #pragma unroll
        for (int t = 0; t < 13; ++t)
            KEEP(W[g][t]);

    const int pstA[4] = {0, 13, 26, 38};
    const int pstq = pstA[q];         // dword (pair) offset of this lane's h chunk
    const int goA = q * 100 + d;      // this lane's primary gate slot in a P row

    // merged secondary stream: q0 -> P u-gate (stride 500), q2 -> enc c2 (stride 200),
    // q1/q3 -> P[0] (stride 0, dead value, keeps loads uniform & unconditional)
    const float* pA0 = P + goA;
    const float* pX0 = (q == 0) ? (P + 400 + d)
                     : (q == 2) ? (enc + 100 + d) : P;
    const int strX   = (q == 0) ? PSTRIDE : (q == 2) ? 200 : 0;

    float c_reg = 0.f;                 // cell state, lives at q1
    if (act && q == 1) c_reg = enc[100 + d];
    if (q == 0) hbufh[0][d] = (_Float16)enc[d];   // d<128, enc row 0 has 200 elems

    // fill the 4-deep ring: steps 1..4 -> slots 0..3
    float pa[4], px[4];
    #pragma unroll
    for (int kk = 1; kk <= 4; ++kk) {
        pa[kk - 1] = pA0[(size_t)kk * PSTRIDE];
        px[kk - 1] = pX0[(size_t)kk * strX];
    }
    const float* pPA = pA0 + (size_t)5 * PSTRIDE;   // next prefetch = step 5
    const float* pPX = pX0 + (size_t)5 * strX;
    float* pMst = M + 200 + ((q == 3) ? d : 100 + d);   // step-1 store slot (q1:c, q3:h)
    BAR();

    // main loop: 8190 iterations x 4 steps = steps 1..32760
    for (int base = 1; base <= KMAX - 9; base += 4) {
        BODY(0, true);
        BODY(1, true);
        BODY(2, true);
        BODY(3, true);
    }
    // tail: steps 32761..32766 (slots 0,1 reloaded for 32765/32766)
    BODY(0, true);
    BODY(1, true);
    BODY(2, false);
    BODY(3, false);
    BODY(0, false);
    BODY(1, false);
}

// ---------------- per-step CE losses + reduction ----------------
__global__ __launch_bounds__(256) void loss_kernel(const float* __restrict__ TM,
    const float* __restrict__ TE, const float* __restrict__ msAB, const float* __restrict__ msBC,
    const float* __restrict__ b_act, const float* __restrict__ b_lab, const float* __restrict__ b_dir,
    const int* __restrict__ ga, const int* __restrict__ gl, const int* __restrict__ gd,
    float* __restrict__ out)
{
    const int t = blockIdx.x * 256 + threadIdx.x;
    float loss = 0.f;
    if (t < N_STEPS) {
        const float *v1, *v0, *vb;
        if (t == 0)      { v1 = msAB; v0 = msAB + 24; vb = TE + 24; }
        else if (t == 1) { v1 = msAB; v0 = TE;        vb = TE + 48 + 24; }
        else if ((t & 1) == 0) {
            const int k = t >> 1;
            v1 = TM + (size_t)(k - 1) * 48;
            v0 = TE + (size_t)k * 48;
            vb = (k < N_EDUS - 1) ? (TE + (size_t)(k + 1) * 48 + 24) : (msBC + 24);
        } else {
            const int k = t >> 1;
            v1 = msAB;
            v0 = TM + (size_t)k * 48 + 24;
            vb = TE + (size_t)(k + 1) * 48 + 24;
        }
        float l[24];
        #pragma unroll
        for (int j = 0; j < 24; ++j) l[j] = v1[j] + v0[j] + vb[j];
        l[0] += b_act[0]; l[1] += b_act[1];
        #pragma unroll
        for (int j = 0; j < 19; ++j) l[2 + j] += b_lab[j];
        #pragma unroll
        for (int j = 0; j < 3; ++j) l[21 + j] += b_dir[j];
        const int ya = ga[t], yl = gl[t], yd = gd[t];
        {
            const float m = fmaxf(l[0], l[1]);
            const float sum = __expf(l[0] - m) + __expf(l[1] - m);
            loss += m + __logf(sum) - (ya == 0 ? l[0] : l[1]);
        }
        {
            float m = l[2];
            #pragma unroll
            for (int j = 1; j < 19; ++j) m = fmaxf(m, l[2 + j]);
            float sum = 0.f, ly = 0.f;
            #pragma unroll
            for (int j = 0; j < 19; ++j) {
                sum += __expf(l[2 + j] - m);
                if (j == yl) ly = l[2 + j];
            }
            loss += m + __logf(sum) - ly;
        }
        {
            const float m = fmaxf(fmaxf(l[21], l[22]), l[23]);
            const float sum = __expf(l[21] - m) + __expf(l[22] - m) + __expf(l[23] - m);
            const float ly = (yd == 0) ? l[21] : (yd == 1 ? l[22] : l[23]);
            loss += m + __logf(sum) - ly;
        }
    }
    #pragma unroll
    for (int off = 32; off > 0; off >>= 1) loss += __shfl_down(loss, off, 64);
    __shared__ float wsum[4];
    const int lane = threadIdx.x & 63, wv = threadIdx.x >> 6;
    if (lane == 0) wsum[wv] = loss;
    __syncthreads();
    if (threadIdx.x == 0) atomicAdd(out, wsum[0] + wsum[1] + wsum[2] + wsum[3]);
}

// ---------------- launch ----------------
extern "C" void kernel_launch(void* const* d_in, const int* in_sizes, int n_in,
                              void* d_out, int out_size, void* d_ws, size_t ws_size,
                              hipStream_t stream) {
    const float* enc_cls = (const float*)d_in[0];
    const float* W_proj  = (const float*)d_in[1];
    const float* b_proj  = (const float*)d_in[2];
    const float* miss    = (const float*)d_in[3];
    const float* W_act   = (const float*)d_in[4];
    const float* b_act   = (const float*)d_in[5];
    const float* W_lab   = (const float*)d_in[6];
    const float* b_lab   = (const float*)d_in[7];
    const float* W_dir   = (const float*)d_in[8];
    const float* b_dir   = (const float*)d_in[9];
    const float* W_tree  = (const float*)d_in[10];
    const float* b_tree  = (const float*)d_in[11];
    const int*   ga      = (const int*)d_in[12];
    const int*   gl      = (const int*)d_in[13];
    const int*   gd      = (const int*)d_in[14];
    float* out = (float*)d_out;

    float* ws   = (float*)d_ws;
    float* enc  = ws;                         // 32768*200
    float* Mar  = ws + 6553600;               // 32767*200
    float* P    = ws + 13107000;              // 32767*500 (row 0 unused)
    float* WAB  = ws + 29490500;              // 48*200
    float* WBC  = WAB + 9600;                 // 48*200
    float* msAB = WBC + 9600;                 // 48
    float* msBC = msAB + 48;                  // 48
    unsigned int* W16 = (unsigned int*)(msBC + 48);   // 33,280 dwords
    float* TM = P;                            // 32767*48 (overlays dead P)
    float* TE = P + 1572816;                  // 32768*48

    gemm_bt<<<dim3(512, 4, 1), 256, 0, stream>>>(enc_cls, 768, W_proj, 768, b_proj,
                                                 enc, 200, N_EDUS, 200, 768);
    gemm_bt<<<dim3(512, 8, 1), 256, 0, stream>>>(enc + 200, 200, W_tree + 100, 200, b_tree,
                                                 P + PSTRIDE, PSTRIDE, KMAX, 500, 100);
    prep_kernel<<<1, 256, 0, stream>>>(W_act, W_lab, W_dir, miss, WAB, WBC, msAB, msBC, out);
    pack_w16<<<130, 256, 0, stream>>>(W_tree, W16);
    chain_kernel<<<1, 512, 0, stream>>>(enc, W16, P, Mar);
    gemm_bt<<<dim3(512, 1, 1), 256, 0, stream>>>(Mar, 200, WAB, 200, nullptr,
                                                 TM, 48, KMAX + 1, 48, 200);
    gemm_bt<<<dim3(512, 1, 1), 256, 0, stream>>>(enc, 200, WBC, 200, nullptr,
                                                 TE, 48, N_EDUS, 48, 200);
    loss_kernel<<<dim3(256, 1, 1), 256, 0, stream>>>(TM, TE, msAB, msBC,
                                                     b_act, b_lab, b_dir, ga, gl, gd, out);
}

// Round 9
// 20579.420 us; speedup vs baseline: 1.5755x; 1.0144x over previous
//
#include <hip/hip_runtime.h>
#include <cstdint>

#define HID 200
#define HALF 100
#define N_EDUS 32768
#define N_STEPS (2*N_EDUS - 1)   // 65535
#define KMAX 32766               // chain computes M_1..M_32766 (M_0 = enc[0])
#define PSTRIDE 500

typedef __fp16 h2v __attribute__((ext_vector_type(2)));

// ---------------- generic tiled GEMM: C[m][n] = bias[n] + sum_k A[m][k]*B[n][k] ----------------
__global__ __launch_bounds__(256) void gemm_bt(const float* __restrict__ A, int lda,
    const float* __restrict__ B, int ldb, const float* __restrict__ bias,
    float* __restrict__ C, int ldc, int M, int N, int K)
{
    __shared__ float As[32][68];
    __shared__ float Bs[32][68];
    const int tid = threadIdx.x;
    const int tx = tid & 15, ty = tid >> 4;
    const int m0 = blockIdx.x * 64, n0 = blockIdx.y * 64;
    float acc[4][4] = {};
    for (int kc = 0; kc < K; kc += 32) {
        const int kk = tid & 31, r0 = tid >> 5;
        #pragma unroll
        for (int p = 0; p < 8; ++p) {
            const int mm = r0 + p * 8;
            const int m = m0 + mm, n = n0 + mm, kg = kc + kk;
            As[kk][mm] = (m < M && kg < K) ? A[(size_t)m * lda + kg] : 0.f;
            Bs[kk][mm] = (n < N && kg < K) ? B[(size_t)n * ldb + kg] : 0.f;
        }
        __syncthreads();
        #pragma unroll
        for (int kk2 = 0; kk2 < 32; ++kk2) {
            const float4 a = *(const float4*)&As[kk2][tx * 4];
            const float4 b = *(const float4*)&Bs[kk2][ty * 4];
            const float av[4] = {a.x, a.y, a.z, a.w};
            const float bv[4] = {b.x, b.y, b.z, b.w};
            #pragma unroll
            for (int r = 0; r < 4; ++r)
                #pragma unroll
                for (int c = 0; c < 4; ++c)
                    acc[r][c] += av[r] * bv[c];
        }
        __syncthreads();
    }
    #pragma unroll
    for (int r = 0; r < 4; ++r) {
        const int m = m0 + tx * 4 + r;
        if (m >= M) continue;
        #pragma unroll
        for (int c = 0; c < 4; ++c) {
            const int n = n0 + ty * 4 + c;
            if (n < N) C[(size_t)m * ldc + n] = acc[r][c] + (bias ? bias[n] : 0.f);
        }
    }
}

// ---------------- prep (loss weight stacking + missing projections) ----------------
__global__ void prep_kernel(const float* __restrict__ W_act, const float* __restrict__ W_lab,
    const float* __restrict__ W_dir, const float* __restrict__ miss,
    float* __restrict__ WAB, float* __restrict__ WBC,
    float* __restrict__ msAB, float* __restrict__ msBC, float* __restrict__ out)
{
    const int tid = threadIdx.x;
    if (tid == 0) out[0] = 0.f;
    for (int i = tid; i < 48 * 200; i += 256) {
        const int r = i / 200, c = i % 200;
        const int rr = r % 24;
        const float* src = (rr < 2) ? (W_act + rr * 600)
                         : (rr < 21) ? (W_lab + (rr - 2) * 600)
                                     : (W_dir + (rr - 21) * 600);
        WAB[i] = src[c + (r < 24 ? 0 : 200)];
        WBC[i] = src[c + (r < 24 ? 200 : 400)];
    }
    __syncthreads();
    if (tid < 48) {
        float sA = 0.f, sB = 0.f;
        for (int c = 0; c < 200; ++c) {
            sA += WAB[tid * 200 + c] * miss[c];
            sB += WBC[tid * 200 + c] * miss[c];
        }
        msAB[tid] = sA;
        msBC[tid] = sB;
    }
}

// ---------------- pack W_tree[:,0:100] into per-(d,q) f16-pair layout ----------------
__global__ __launch_bounds__(256) void pack_w16(const float* __restrict__ W_tree,
                                                unsigned int* __restrict__ W16)
{
    const int i = blockIdx.x * 256 + threadIdx.x;   // 5*4*13*128 = 33280
    if (i >= 5 * 4 * 13 * 128) return;
    const int d = i & 127, r = i >> 7;
    const int t = r % 13, gq = r / 13, q = gq & 3, g = gq >> 2;
    const int pst[4] = {0, 13, 26, 38}, pct[4] = {13, 13, 12, 12};
    unsigned int val = 0;
    if (t < pct[q] && d < 100) {
        const int p = pst[q] + t;
        const float w0 = W_tree[(size_t)(g * 100 + d) * 200 + 2 * p];
        const float w1 = W_tree[(size_t)(g * 100 + d) * 200 + 2 * p + 1];
        h2v h = __builtin_amdgcn_cvt_pkrtz(w0, w1);
        __builtin_memcpy(&val, &h, 4);
    }
    W16[i] = val;
}

// ---------------- sequential treelstm chain ----------------
__device__ __forceinline__ float sigf(float x) {
    return __builtin_amdgcn_rcpf(1.f + __expf(-x));
}
__device__ __forceinline__ float tanhf_(float x) {
    return 1.f - 2.f * __builtin_amdgcn_rcpf(1.f + __expf(2.f * x));
}
__device__ __forceinline__ h2v u2h(unsigned int u) { h2v h; __builtin_memcpy(&h, &u, 4); return h; }

// raw barrier: drain LDS only, leave global prefetch loads (vmcnt) in flight
#define BAR() asm volatile("s_waitcnt lgkmcnt(0)\n\ts_barrier" ::: "memory")
#define KEEP(x) asm volatile("" : "+v"(x))
// quad_perm butterfly add via DPP (xor1 = 0xB1, xor2 = 0x4E)
#define DPPADD(x, c) ((x) + __int_as_float(__builtin_amdgcn_update_dpp(0, __float_as_int(x), (c), 0xF, 0xF, true)))

// One chain step. U = ring slot (0..3) & LDS parity (U&1), compile-time.
// t-outer dot: one h-word live at a time (kills the hw[13] live array that
// overflowed the 88-VGPR budget into AGPR park+readback). 5 parallel acc chains.
#define BODY(U, DOLOAD) \
{ \
    const unsigned int* hb = (const unsigned int*)(&hbufh[(U) & 1][0]) + pstq; \
    float ac0 = 0.f, ac1 = 0.f, ac2 = 0.f, ac3 = 0.f, ac4 = 0.f; \
    _Pragma("unroll") \
    for (int t = 0; t < 13; ++t) { \
        const h2v hwt = u2h(hb[t]); \
        ac0 = __builtin_amdgcn_fdot2(u2h(W[0][t]), hwt, ac0, false); \
        ac1 = __builtin_amdgcn_fdot2(u2h(W[1][t]), hwt, ac1, false); \
        ac2 = __builtin_amdgcn_fdot2(u2h(W[2][t]), hwt, ac2, false); \
        ac3 = __builtin_amdgcn_fdot2(u2h(W[3][t]), hwt, ac3, false); \
        ac4 = __builtin_amdgcn_fdot2(u2h(W[4][t]), hwt, ac4, false); \
    } \
    ac0 = DPPADD(ac0, 0xB1); ac0 = DPPADD(ac0, 0x4E); \
    ac1 = DPPADD(ac1, 0xB1); ac1 = DPPADD(ac1, 0x4E); \
    ac2 = DPPADD(ac2, 0xB1); ac2 = DPPADD(ac2, 0x4E); \
    ac3 = DPPADD(ac3, 0xB1); ac3 = DPPADD(ac3, 0x4E); \
    ac4 = DPPADD(ac4, 0xB1); ac4 = DPPADD(ac4, 0x4E); \
    const float prim = (q == 0) ? ac0 : (q == 1) ? ac1 : (q == 2) ? ac2 : ac3; \
    const float sg = sigf(prim + pa[U]); \
    const float mult = (q == 0) ? tanhf_(ac4 + px[U]) \
                     : (q == 1) ? c_reg \
                     : (q == 2) ? px[U] : 0.f; \
    if (DOLOAD) { pa[U] = *pPA; pPA += PSTRIDE; px[U] = *pPX; pPX += strX; } \
    float a = sg * mult; \
    a = DPPADD(a, 0xB1); \
    a = DPPADD(a, 0x4E); \
    if (q == 3) { \
        const float h = sg * tanhf_(a); \
        hbufh[((U) & 1) ^ 1][d] = (_Float16)h; \
        if (act) *pMst = h; \
    } else if (q == 1) { \
        c_reg = a; \
        if (act) *pMst = a; \
    } \
    pMst += 200; \
    BAR(); \
}

__attribute__((amdgpu_flat_work_group_size(512, 512), amdgpu_waves_per_eu(2, 2)))
__global__ void chain_kernel(const float* __restrict__ enc,
    const unsigned int* __restrict__ W16, const float* __restrict__ P, float* __restrict__ M)
{
    const int T = threadIdx.x;
    const int d = T >> 2, q = T & 3;
    const bool act = (d < 100);
    __shared__ _Float16 hbufh[2][128];

    if (T < 200) M[T] = enc[T];   // M_0 = enc[0]

    unsigned int W[5][13];
    #pragma unroll
    for (int g = 0; g < 5; ++g)
        #pragma unroll
        for (int t = 0; t < 13; ++t)
            W[g][t] = W16[(size_t)(((g * 4 + q) * 13 + t) * 128) + d];
    #pragma unroll
    for (int g = 0; g < 5; ++g)
        #pragma unroll
        for (int t = 0; t < 13; ++t)
            KEEP(W[g][t]);

    const int pstA[4] = {0, 13, 26, 38};
    const int pstq = pstA[q];         // dword (pair) offset of this lane's h chunk
    const int goA = q * 100 + d;      // this lane's primary gate slot in a P row

    // merged secondary stream: q0 -> P u-gate (stride 500), q2 -> enc c2 (stride 200),
    // q1/q3 -> P[0] (stride 0, dead value, keeps loads uniform & unconditional)
    const float* pA0 = P + goA;
    const float* pX0 = (q == 0) ? (P + 400 + d)
                     : (q == 2) ? (enc + 100 + d) : P;
    const int strX   = (q == 0) ? PSTRIDE : (q == 2) ? 200 : 0;

    float c_reg = 0.f;                 // cell state, lives at q1
    if (act && q == 1) c_reg = enc[100 + d];
    if (q == 0) hbufh[0][d] = (_Float16)enc[d];   // d<128, enc row 0 has 200 elems

    // fill the 4-deep ring: steps 1..4 -> slots 0..3
    float pa[4], px[4];
    #pragma unroll
    for (int kk = 1; kk <= 4; ++kk) {
        pa[kk - 1] = pA0[(size_t)kk * PSTRIDE];
        px[kk - 1] = pX0[(size_t)kk * strX];
    }
    const float* pPA = pA0 + (size_t)5 * PSTRIDE;   // next prefetch = step 5
    const float* pPX = pX0 + (size_t)5 * strX;
    float* pMst = M + 200 + ((q == 3) ? d : 100 + d);   // step-1 store slot (q1:c, q3:h)
    BAR();

    // main loop: 8190 iterations x 4 steps = steps 1..32760
    for (int base = 1; base <= KMAX - 9; base += 4) {
        BODY(0, true);
        BODY(1, true);
        BODY(2, true);
        BODY(3, true);
    }
    // tail: steps 32761..32766 (slots 0,1 reloaded for 32765/32766)
    BODY(0, true);
    BODY(1, true);
    BODY(2, false);
    BODY(3, false);
    BODY(0, false);
    BODY(1, false);
}

// ---------------- per-step CE losses + reduction ----------------
__global__ __launch_bounds__(256) void loss_kernel(const float* __restrict__ TM,
    const float* __restrict__ TE, const float* __restrict__ msAB, const float* __restrict__ msBC,
    const float* __restrict__ b_act, const float* __restrict__ b_lab, const float* __restrict__ b_dir,
    const int* __restrict__ ga, const int* __restrict__ gl, const int* __restrict__ gd,
    float* __restrict__ out)
{
    const int t = blockIdx.x * 256 + threadIdx.x;
    float loss = 0.f;
    if (t < N_STEPS) {
        const float *v1, *v0, *vb;
        if (t == 0)      { v1 = msAB; v0 = msAB + 24; vb = TE + 24; }
        else if (t == 1) { v1 = msAB; v0 = TE;        vb = TE + 48 + 24; }
        else if ((t & 1) == 0) {
            const int k = t >> 1;
            v1 = TM + (size_t)(k - 1) * 48;
            v0 = TE + (size_t)k * 48;
            vb = (k < N_EDUS - 1) ? (TE + (size_t)(k + 1) * 48 + 24) : (msBC + 24);
        } else {
            const int k = t >> 1;
            v1 = msAB;
            v0 = TM + (size_t)k * 48 + 24;
            vb = TE + (size_t)(k + 1) * 48 + 24;
        }
        float l[24];
        #pragma unroll
        for (int j = 0; j < 24; ++j) l[j] = v1[j] + v0[j] + vb[j];
        l[0] += b_act[0]; l[1] += b_act[1];
        #pragma unroll
        for (int j = 0; j < 19; ++j) l[2 + j] += b_lab[j];
        #pragma unroll
        for (int j = 0; j < 3; ++j) l[21 + j] += b_dir[j];
        const int ya = ga[t], yl = gl[t], yd = gd[t];
        {
            const float m = fmaxf(l[0], l[1]);
            const float sum = __expf(l[0] - m) + __expf(l[1] - m);
            loss += m + __logf(sum) - (ya == 0 ? l[0] : l[1]);
        }
        {
            float m = l[2];
            #pragma unroll
            for (int j = 1; j < 19; ++j) m = fmaxf(m, l[2 + j]);
            float sum = 0.f, ly = 0.f;
            #pragma unroll
            for (int j = 0; j < 19; ++j) {
                sum += __expf(l[2 + j] - m);
                if (j == yl) ly = l[2 + j];
            }
            loss += m + __logf(sum) - ly;
        }
        {
            const float m = fmaxf(fmaxf(l[21], l[22]), l[23]);
            const float sum = __expf(l[21] - m) + __expf(l[22] - m) + __expf(l[23] - m);
            const float ly = (yd == 0) ? l[21] : (yd == 1 ? l[22] : l[23]);
            loss += m + __logf(sum) - ly;
        }
    }
    #pragma unroll
    for (int off = 32; off > 0; off >>= 1) loss += __shfl_down(loss, off, 64);
    __shared__ float wsum[4];
    const int lane = threadIdx.x & 63, wv = threadIdx.x >> 6;
    if (lane == 0) wsum[wv] = loss;
    __syncthreads();
    if (threadIdx.x == 0) atomicAdd(out, wsum[0] + wsum[1] + wsum[2] + wsum[3]);
}

// ---------------- launch ----------------
extern "C" void kernel_launch(void* const* d_in, const int* in_sizes, int n_in,
                              void* d_out, int out_size, void* d_ws, size_t ws_size,
                              hipStream_t stream) {
    const float* enc_cls = (const float*)d_in[0];
    const float* W_proj  = (const float*)d_in[1];
    const float* b_proj  = (const float*)d_in[2];
    const float* miss    = (const float*)d_in[3];
    const float* W_act   = (const float*)d_in[4];
    const float* b_act   = (const float*)d_in[5];
    const float* W_lab   = (const float*)d_in[6];
    const float* b_lab   = (const float*)d_in[7];
    const float* W_dir   = (const float*)d_in[8];
    const float* b_dir   = (const float*)d_in[9];
    const float* W_tree  = (const float*)d_in[10];
    const float* b_tree  = (const float*)d_in[11];
    const int*   ga      = (const int*)d_in[12];
    const int*   gl      = (const int*)d_in[13];
    const int*   gd      = (const int*)d_in[14];
    float* out = (float*)d_out;

    float* ws   = (float*)d_ws;
    float* enc  = ws;                         // 32768*200
    float* Mar  = ws + 6553600;               // 32767*200
    float* P    = ws + 13107000;              // 32767*500 (row 0 unused)
    float* WAB  = ws + 29490500;              // 48*200
    float* WBC  = WAB + 9600;                 // 48*200
    float* msAB = WBC + 9600;                 // 48
    float* msBC = msAB + 48;                  // 48
    unsigned int* W16 = (unsigned int*)(msBC + 48);   // 33,280 dwords
    float* TM = P;                            // 32767*48 (overlays dead P)
    float* TE = P + 1572816;                  // 32768*48

    gemm_bt<<<dim3(512, 4, 1), 256, 0, stream>>>(enc_cls, 768, W_proj, 768, b_proj,
                                                 enc, 200, N_EDUS, 200, 768);
    gemm_bt<<<dim3(512, 8, 1), 256, 0, stream>>>(enc + 200, 200, W_tree + 100, 200, b_tree,
                                                 P + PSTRIDE, PSTRIDE, KMAX, 500, 100);
    prep_kernel<<<1, 256, 0, stream>>>(W_act, W_lab, W_dir, miss, WAB, WBC, msAB, msBC, out);
    pack_w16<<<130, 256, 0, stream>>>(W_tree, W16);
    chain_kernel<<<1, 512, 0, stream>>>(enc, W16, P, Mar);
    gemm_bt<<<dim3(512, 1, 1), 256, 0, stream>>>(Mar, 200, WAB, 200, nullptr,
                                                 TM, 48, KMAX + 1, 48, 200);
    gemm_bt<<<dim3(512, 1, 1), 256, 0, stream>>>(enc, 200, WBC, 200, nullptr,
                                                 TE, 48, N_EDUS, 48, 200);
    loss_kernel<<<dim3(256, 1, 1), 256, 0, stream>>>(TM, TE, msAB, msBC,
                                                     b_act, b_lab, b_dir, ga, gl, gd, out);
}